// Round 4
// baseline (156.904 us; speedup 1.0000x reference)
//
#include <hip/hip_runtime.h>
#include <math.h>

constexpr int NB = 1024;   // batch
constexpr int NT = 256;    // topic_size
constexpr int NE = 300;    // embedding_size
constexpr int NBATCH = 4;  // batches per block
constexpr unsigned GRID = NB / NBATCH;  // 256 blocks, 1/CU -> co-resident

#if defined(__has_builtin)
#if __has_builtin(__builtin_amdgcn_exp2f)
#define EXP2F(x) __builtin_amdgcn_exp2f(x)
#else
#define EXP2F(x) exp2f(x)
#endif
#if __has_builtin(__builtin_amdgcn_logf)
#define LOG2F(x) __builtin_amdgcn_logf(x)
#else
#define LOG2F(x) log2f(x)
#endif
#else
#define EXP2F(x) exp2f(x)
#define LOG2F(x) log2f(x)
#endif

__device__ __forceinline__ float rdlane(float v, int l) {
  return __uint_as_float(__builtin_amdgcn_readlane(__float_as_uint(v), l));
}

// Device-scope grid barrier (proven correct in round 3).
__device__ __forceinline__ void grid_barrier(unsigned* cnt, unsigned n) {
  __syncthreads();
  if (threadIdx.x == 0) {
    __hip_atomic_fetch_add(cnt, 1u, __ATOMIC_RELEASE, __HIP_MEMORY_SCOPE_AGENT);
    while (__hip_atomic_load(cnt, __ATOMIC_ACQUIRE, __HIP_MEMORY_SCOPE_AGENT) < n)
      __builtin_amdgcn_s_sleep(2);
  }
  __syncthreads();
}

__global__ __launch_bounds__(1024) void k_fused(
    const float* __restrict__ req, const float* __restrict__ wsdl,
    const float* __restrict__ TE, const float* __restrict__ wf,
    const float* __restrict__ bf, float* __restrict__ out,
    float* __restrict__ Mt, float* __restrict__ Mrow, float* __restrict__ G2,
    float* __restrict__ u2, float* __restrict__ Gd, float* __restrict__ Gof,
    unsigned* __restrict__ bar, unsigned* __restrict__ stat) {
  __shared__ __align__(16) float4 red4[4][NT][2];
  __shared__ __align__(16) float4 L4_s[NT];
  __shared__ __align__(16) float4 qv4_s[NT];
  __shared__ float fin[16][12];

  const float LOG2E = 1.4426950408889634f;
  int tid = threadIdx.x;
  int q = tid >> 8;    // quad 0..3
  int c = tid & 255;   // column / lane-c
  int lane = tid & 63;
  int wid = tid >> 6;
  int blk = blockIdx.x;

  // ===== Phase M: column blk of M, i.e. Mt[blk][t] = sum_e TE[e,t]*wf[blk,e]
  // TE coalesced (lane=t=c); wf row uniform (const input -> s_load batched).
  {
    float acc = 0.f;
    const float* wrow = wf + blk * NE;
    int e0 = q * 75;  // NE/4 == 75 exactly
#pragma unroll 5
    for (int e = e0; e < e0 + 75; ++e)
      acc = fmaf(TE[e * NT + c], wrow[e], acc);
    red4[q][c][0].x = acc;
  }
  __syncthreads();
  if (q == 0) {
    float s = red4[0][c][0].x + red4[1][c][0].x + red4[2][c][0].x + red4[3][c][0].x;
    Mt[blk * NT + c] = s;    // transposed: coalesced write
    Mrow[c * NT + blk] = s;  // row-major: scattered, one-time
  }
  grid_barrier(bar + 0, GRID);

  // ===== Phase G: row blk of G2 = (M M^T)*log2e; also Gd (diag), Gof (off-diag
  // row max, == column max by symmetry), u2, and global Upos atomic.
  {
    float acc = 0.f;
    int k0 = q * 64;
#pragma unroll 8
    for (int kk = 0; kk < 64; ++kk) {
      int k = k0 + kk;
      acc = fmaf(Mt[k * NT + blk], Mt[k * NT + c], acc);  // broadcast + coalesced
    }
    red4[q][c][0].x = acc;
  }
  __syncthreads();
  if (q == 0) {
    float g = (red4[0][c][0].x + red4[1][c][0].x + red4[2][c][0].x +
               red4[3][c][0].x) * LOG2E;
    G2[blk * NT + c] = g;
    if (c == blk) Gd[blk] = g;
    float v = (c == blk) ? -3.0e38f : g;
#pragma unroll
    for (int off = 32; off > 0; off >>= 1) v = fmaxf(v, __shfl_down(v, off, 64));
    if (lane == 0) fin[wid][0] = v;
    float p = Mrow[blk * NT + c] * bf[c];
#pragma unroll
    for (int off = 32; off > 0; off >>= 1) p += __shfl_down(p, off, 64);
    if (lane == 0) fin[wid][1] = p;
  }
  __syncthreads();
  if (tid == 0) {
    float gof = fmaxf(fmaxf(fin[0][0], fin[1][0]), fmaxf(fin[2][0], fin[3][0]));
    Gof[blk] = fmaxf(gof, 0.f);
    float uv = (fin[0][1] + fin[1][1] + fin[2][1] + fin[3][1]) * LOG2E;
    u2[blk] = uv;
    atomicMax(stat, __float_as_uint(fmaxf(uv, 0.f)));  // Upos >= 0
  }
  grid_barrier(bar + 1, GRID);

  // ===== Phase main: 4 batches per block, quad q covers index range [64q,64q+64)
  int b0 = blk * NBATCH;
  int i0 = q * 64;

  float wb[4], rc[4];
#pragma unroll
  for (int bb = 0; bb < 4; ++bb) {
    wb[bb] = wsdl[(b0 + bb) * NT + c];  // coalesced
    rc[bb] = req[(b0 + bb) * NT + c];
  }
  float uc = u2[c];
  float gd = Gd[c], gof = Gof[c];
  float up = __uint_as_float(stat[0]);

  // Safe softmax upper bound per (batch, column c):
  //   m^ = max( r_c*(w_c*G_cc + u_c),  w_c*max(0,offdiag col max) + max(0,max u) )
  // >= true column max (r,w in [0,1]); overestimate bounded ~40 log2 units.
  float mh[4];
#pragma unroll
  for (int bb = 0; bb < 4; ++bb) {
    float diag = rc[bb] * fmaf(wb[bb], gd, uc);
    float offb = fmaf(wb[bb], gof, up);
    mh[bb] = fmaxf(diag, offb);
  }

  // Lane-distributed vectors for readlane broadcast (index range of this quad).
  float r_vec[4], w_vec[4];
#pragma unroll
  for (int bb = 0; bb < 4; ++bb) {
    r_vec[bb] = req[(b0 + bb) * NT + i0 + lane];
    w_vec[bb] = wsdl[(b0 + bb) * NT + i0 + lane];
  }
  float u_vec = u2[i0 + lane];

  // ---- Pass D: column denominators (no memory broadcasts in loop) ----
  float d0 = 0.f, d1 = 0.f, d2 = 0.f, d3 = 0.f;
#pragma unroll 8
  for (int ii = 0; ii < 64; ++ii) {
    float g = G2[(i0 + ii) * NT + c];  // coalesced
    float su = rdlane(u_vec, ii);
    float s0 = rdlane(r_vec[0], ii), s1 = rdlane(r_vec[1], ii);
    float s2 = rdlane(r_vec[2], ii), s3 = rdlane(r_vec[3], ii);
    d0 += EXP2F(fmaf(s0, fmaf(wb[0], g, su), -mh[0]));
    d1 += EXP2F(fmaf(s1, fmaf(wb[1], g, su), -mh[1]));
    d2 += EXP2F(fmaf(s2, fmaf(wb[2], g, su), -mh[2]));
    d3 += EXP2F(fmaf(s3, fmaf(wb[3], g, su), -mh[3]));
  }
  red4[q][c][0] = make_float4(d0, d1, d2, d3);
  __syncthreads();
  if (q == 0) {
    float4 a = red4[0][c][0], b = red4[1][c][0];
    float4 e = red4[2][c][0], f = red4[3][c][0];
    float4 L;
    L.x = mh[0] + LOG2F(a.x + b.x + e.x + f.x);
    L.y = mh[1] + LOG2F(a.y + b.y + e.y + f.y);
    L.z = mh[2] + LOG2F(a.z + b.z + e.z + f.z);
    L.w = mh[3] + LOG2F(a.w + b.w + e.w + f.w);
    L4_s[c] = L;
  }
  __syncthreads();
  float4 Lq = L4_s[i0 + lane];  // transpose pickup: L for column i0+lane
  float Lv0 = Lq.x, Lv1 = Lq.y, Lv2 = Lq.z, Lv3 = Lq.w;

  // ---- Pass S: row-sums of softmaxed att (row i=c), j over quad range ----
  float S0 = 0.f, S1 = 0.f, S2 = 0.f, S3 = 0.f;
#pragma unroll 8
  for (int jj = 0; jj < 64; ++jj) {
    float g = G2[(i0 + jj) * NT + c];  // G[c][j] by symmetry; coalesced
    float w0 = rdlane(w_vec[0], jj), w1 = rdlane(w_vec[1], jj);
    float w2 = rdlane(w_vec[2], jj), w3 = rdlane(w_vec[3], jj);
    float l0 = rdlane(Lv0, jj), l1 = rdlane(Lv1, jj);
    float l2 = rdlane(Lv2, jj), l3 = rdlane(Lv3, jj);
    S0 += EXP2F(fmaf(rc[0], fmaf(w0, g, uc), -l0));
    S1 += EXP2F(fmaf(rc[1], fmaf(w1, g, uc), -l1));
    S2 += EXP2F(fmaf(rc[2], fmaf(w2, g, uc), -l2));
    S3 += EXP2F(fmaf(rc[3], fmaf(w3, g, uc), -l3));
  }
  red4[q][c][0] = make_float4(S0, S1, S2, S3);
  __syncthreads();
  if (q == 0) {
    float4 a = red4[0][c][0], b = red4[1][c][0];
    float4 e = red4[2][c][0], f = red4[3][c][0];
    float4 qv;
    qv.x = (a.x + b.x + e.x + f.x) * rc[0];
    qv.y = (a.y + b.y + e.y + f.y) * rc[1];
    qv.z = (a.z + b.z + e.z + f.z) * rc[2];
    qv.w = (a.w + b.w + e.w + f.w) * rc[3];
    qv4_s[c] = qv;
  }
  __syncthreads();
  float4 Qq = qv4_s[i0 + lane];
  float Qv0 = Qq.x, Qv1 = Qq.y, Qv2 = Qq.z, Qv3 = Qq.w;

  // ---- Pass B: ave_req = (r/T)@M + bf, ave_wsdl = (qv/T)@M + bf ----
  float a0 = 0.f, a1 = 0.f, a2 = 0.f, a3 = 0.f;
  float y0 = 0.f, y1 = 0.f, y2 = 0.f, y3 = 0.f;
#pragma unroll 8
  for (int tt = 0; tt < 64; ++tt) {
    float mk = Mrow[(i0 + tt) * NT + c];  // coalesced
    float s0 = rdlane(r_vec[0], tt), s1 = rdlane(r_vec[1], tt);
    float s2 = rdlane(r_vec[2], tt), s3 = rdlane(r_vec[3], tt);
    float p0 = rdlane(Qv0, tt), p1 = rdlane(Qv1, tt);
    float p2 = rdlane(Qv2, tt), p3 = rdlane(Qv3, tt);
    a0 = fmaf(s0, mk, a0); y0 = fmaf(p0, mk, y0);
    a1 = fmaf(s1, mk, a1); y1 = fmaf(p1, mk, y1);
    a2 = fmaf(s2, mk, a2); y2 = fmaf(p2, mk, y2);
    a3 = fmaf(s3, mk, a3); y3 = fmaf(p3, mk, y3);
  }
  red4[q][c][0] = make_float4(a0, a1, a2, a3);
  red4[q][c][1] = make_float4(y0, y1, y2, y3);
  __syncthreads();
  float st[12];
  {
    float4 A0 = red4[0][c][0], A1 = red4[1][c][0];
    float4 A2 = red4[2][c][0], A3 = red4[3][c][0];
    float4 W0 = red4[0][c][1], W1 = red4[1][c][1];
    float4 W2 = red4[2][c][1], W3 = red4[3][c][1];
    float bfc = bf[c];
    float arT[4], awT[4];
    arT[0] = A0.x + A1.x + A2.x + A3.x; awT[0] = W0.x + W1.x + W2.x + W3.x;
    arT[1] = A0.y + A1.y + A2.y + A3.y; awT[1] = W0.y + W1.y + W2.y + W3.y;
    arT[2] = A0.z + A1.z + A2.z + A3.z; awT[2] = W0.z + W1.z + W2.z + W3.z;
    arT[3] = A0.w + A1.w + A2.w + A3.w; awT[3] = W0.w + W1.w + W2.w + W3.w;
    const float invT = 1.0f / NT;
#pragma unroll
    for (int bb = 0; bb < 4; ++bb) {
      float av = fmaf(arT[bb], invT, bfc);
      float wv = fmaf(awT[bb], invT, bfc);
      st[bb] = av * wv;      // 4x quad replication cancels in the ratio
      st[4 + bb] = av * av;
      st[8 + bb] = wv * wv;
    }
  }
#pragma unroll
  for (int k = 0; k < 12; ++k)
#pragma unroll
    for (int off = 32; off > 0; off >>= 1) st[k] += __shfl_down(st[k], off, 64);
  if (lane == 0)
#pragma unroll
    for (int k = 0; k < 12; ++k) fin[wid][k] = st[k];
  __syncthreads();
  if (tid < NBATCH) {
    int bb = tid;
    float N = 0.f, A = 0.f, C = 0.f;
    for (int w = 0; w < 16; ++w) {
      N += fin[w][bb];
      A += fin[w][4 + bb];
      C += fin[w][8 + bb];
    }
    out[b0 + bb] = N / fmaxf(sqrtf(A) * sqrtf(C), 1e-8f) * 3.0f;
  }
}

extern "C" void kernel_launch(void* const* d_in, const int* in_sizes, int n_in,
                              void* d_out, int out_size, void* d_ws, size_t ws_size,
                              hipStream_t stream) {
  const float* req  = (const float*)d_in[0];
  const float* wsdl = (const float*)d_in[1];
  const float* TE   = (const float*)d_in[2];
  const float* wf   = (const float*)d_in[3];
  const float* bf   = (const float*)d_in[4];
  float* out = (float*)d_out;

  // ws layout: [bar0,bar1,Upos,pad | @256: Mt | Mrow | G2 | u2 | Gd | Gof]
  unsigned* bar  = (unsigned*)d_ws;
  unsigned* stat = bar + 2;
  float* Mt   = (float*)((char*)d_ws + 256);
  float* Mrow = Mt + NT * NT;
  float* G2   = Mrow + NT * NT;
  float* u2   = G2 + NT * NT;
  float* Gd   = u2 + NT;
  float* Gof  = Gd + NT;

  hipMemsetAsync(d_ws, 0, 16, stream);  // zero barriers + Upos (capturable)
  k_fused<<<GRID, 1024, 0, stream>>>(req, wsdl, TE, wf, bf, out, Mt, Mrow, G2,
                                     u2, Gd, Gof, bar, stat);
}

// Round 5
// 126.068 us; speedup vs baseline: 1.2446x; 1.2446x over previous
//
#include <hip/hip_runtime.h>
#include <math.h>

constexpr int NB = 1024;   // batch
constexpr int NT = 256;    // topic_size
constexpr int NE = 300;    // embedding_size
constexpr int NBATCH = 2;  // batches per k_main block

#if defined(__has_builtin)
#if __has_builtin(__builtin_amdgcn_exp2f)
#define EXP2F(x) __builtin_amdgcn_exp2f(x)
#else
#define EXP2F(x) exp2f(x)
#endif
#if __has_builtin(__builtin_amdgcn_logf)
#define LOG2F(x) __builtin_amdgcn_logf(x)
#else
#define LOG2F(x) log2f(x)
#endif
#else
#define EXP2F(x) exp2f(x)
#define LOG2F(x) log2f(x)
#endif

__device__ __forceinline__ float rdlane(float v, int l) {
  return __uint_as_float(__builtin_amdgcn_readlane(__float_as_uint(v), l));
}

// ===== k_M: block f computes M[:,f].  Mt[f][t] (coalesced), Mrow[t][f] (scatter,
// one-time).  wf row is contiguous-uniform -> s_load; TE coalesced over t.
__global__ __launch_bounds__(1024) void k_M(const float* __restrict__ TE,
                                            const float* __restrict__ wf,
                                            float* __restrict__ Mt,
                                            float* __restrict__ Mrow) {
  __shared__ float red[4][NT];
  int tid = threadIdx.x, q = tid >> 8, c = tid & 255, blk = blockIdx.x;
  float acc = 0.f;
  const float* wrow = wf + blk * NE;
  int e0 = q * 75;  // NE/4 == 75
#pragma unroll 5
  for (int e = e0; e < e0 + 75; ++e) acc = fmaf(TE[e * NT + c], wrow[e], acc);
  red[q][c] = acc;
  __syncthreads();
  if (q == 0) {
    float s = red[0][c] + red[1][c] + red[2][c] + red[3][c];
    Mt[blk * NT + c] = s;
    Mrow[c * NT + blk] = s;
  }
}

// ===== k_G: block i computes G2[i,:] = (M M^T)[i,:]*log2e via
// sum_f Mrow[i,f] (contiguous-uniform s_load) * Mt[f,c] (coalesced).
// Also Gd (diag), Gof (off-diag row max, clamped >=0), u2 = (M bf)*log2e,
// and global max(u2,0) via atomicMax.
__global__ __launch_bounds__(1024) void k_G(const float* __restrict__ Mt,
                                            const float* __restrict__ Mrow,
                                            const float* __restrict__ bf,
                                            float* __restrict__ G2,
                                            float* __restrict__ u2,
                                            float* __restrict__ Gd,
                                            float* __restrict__ Gof,
                                            unsigned* __restrict__ stat) {
  __shared__ float red[4][NT];
  __shared__ float fin[4][2];
  const float LOG2E = 1.4426950408889634f;
  int tid = threadIdx.x, q = tid >> 8, c = tid & 255;
  int lane = tid & 63, wid = tid >> 6, blk = blockIdx.x;
  float acc = 0.f;
  const float* mi = Mrow + blk * NT;
  int f0 = q * 64;
#pragma unroll 8
  for (int ff = 0; ff < 64; ++ff) {
    int f = f0 + ff;
    acc = fmaf(mi[f], Mt[f * NT + c], acc);
  }
  red[q][c] = acc;
  __syncthreads();
  if (q == 0) {
    float g = (red[0][c] + red[1][c] + red[2][c] + red[3][c]) * LOG2E;
    G2[blk * NT + c] = g;
    if (c == blk) Gd[blk] = g;
    float v = (c == blk) ? -3.0e38f : g;
#pragma unroll
    for (int off = 32; off > 0; off >>= 1) v = fmaxf(v, __shfl_down(v, off, 64));
    if (lane == 0) fin[wid][0] = v;
    float p = mi[c] * bf[c];  // coalesced read of Mrow[blk,:]
#pragma unroll
    for (int off = 32; off > 0; off >>= 1) p += __shfl_down(p, off, 64);
    if (lane == 0) fin[wid][1] = p;
  }
  __syncthreads();
  if (tid == 0) {
    float gof = fmaxf(fmaxf(fin[0][0], fin[1][0]), fmaxf(fin[2][0], fin[3][0]));
    Gof[blk] = fmaxf(gof, 0.f);
    float uv = (fin[0][1] + fin[1][1] + fin[2][1] + fin[3][1]) * LOG2E;
    u2[blk] = uv;
    atomicMax(stat, __float_as_uint(fmaxf(uv, 0.f)));  // >=0: uint order ok
  }
}

// ===== k_main: 2 batches per block, grid 512 -> 2 blocks/CU (32 waves/CU).
// Quad q covers index range [64q, 64q+64). All loop broadcasts via v_readlane
// from lane-distributed registers; only coalesced global loads in loops.
__global__ __launch_bounds__(1024, 8) void k_main(
    const float* __restrict__ req, const float* __restrict__ wsdl,
    const float* __restrict__ Mrow, const float* __restrict__ G2,
    const float* __restrict__ u2, const float* __restrict__ Gd,
    const float* __restrict__ Gof, const unsigned* __restrict__ stat,
    const float* __restrict__ bf, float* __restrict__ out) {
  __shared__ __align__(16) float2 red2[4][NT][2];
  __shared__ float2 L2s[NT];
  __shared__ float2 Q2s[NT];
  __shared__ float fin[16][6];

  int tid = threadIdx.x, q = tid >> 8, c = tid & 255;
  int lane = tid & 63, wid = tid >> 6;
  int blk = blockIdx.x, b0 = blk * NBATCH, i0 = q * 64;

  float wb0 = wsdl[b0 * NT + c], wb1 = wsdl[(b0 + 1) * NT + c];
  float rc0 = req[b0 * NT + c], rc1 = req[(b0 + 1) * NT + c];
  float uc = u2[c], gd = Gd[c], gof = Gof[c];
  float up = __uint_as_float(stat[0]);

  // Safe softmax upper bound per (batch, column c) — proven absmax 0.0 in r4:
  float mh0 = fmaxf(rc0 * fmaf(wb0, gd, uc), fmaf(wb0, gof, up));
  float mh1 = fmaxf(rc1 * fmaf(wb1, gd, uc), fmaf(wb1, gof, up));

  // Lane-distributed vectors over this quad's index range.
  float rv0 = req[b0 * NT + i0 + lane], rv1 = req[(b0 + 1) * NT + i0 + lane];
  float wv0 = wsdl[b0 * NT + i0 + lane], wv1 = wsdl[(b0 + 1) * NT + i0 + lane];
  float uv = u2[i0 + lane];

  // ---- Pass D: column denominators ----
  float d0 = 0.f, d1 = 0.f;
#pragma unroll 8
  for (int ii = 0; ii < 64; ++ii) {
    float g = G2[(i0 + ii) * NT + c];  // coalesced
    float su = rdlane(uv, ii);
    float s0 = rdlane(rv0, ii), s1 = rdlane(rv1, ii);
    d0 += EXP2F(fmaf(s0, fmaf(wb0, g, su), -mh0));
    d1 += EXP2F(fmaf(s1, fmaf(wb1, g, su), -mh1));
  }
  red2[q][c][0] = make_float2(d0, d1);
  __syncthreads();
  if (q == 0) {
    float2 A = red2[0][c][0], B = red2[1][c][0];
    float2 E = red2[2][c][0], F = red2[3][c][0];
    float2 L;
    L.x = mh0 + LOG2F(A.x + B.x + E.x + F.x);
    L.y = mh1 + LOG2F(A.y + B.y + E.y + F.y);
    L2s[c] = L;
  }
  __syncthreads();
  float2 Lq = L2s[i0 + lane];
  float Lv0 = Lq.x, Lv1 = Lq.y;

  // ---- Pass S: row-sums of softmaxed att (row i=c), j over quad range ----
  float S0 = 0.f, S1 = 0.f;
#pragma unroll 8
  for (int jj = 0; jj < 64; ++jj) {
    float g = G2[(i0 + jj) * NT + c];  // G[c][j] by symmetry; coalesced
    float w0 = rdlane(wv0, jj), w1 = rdlane(wv1, jj);
    float l0 = rdlane(Lv0, jj), l1 = rdlane(Lv1, jj);
    S0 += EXP2F(fmaf(rc0, fmaf(w0, g, uc), -l0));
    S1 += EXP2F(fmaf(rc1, fmaf(w1, g, uc), -l1));
  }
  red2[q][c][0] = make_float2(S0, S1);
  __syncthreads();
  if (q == 0) {
    float2 A = red2[0][c][0], B = red2[1][c][0];
    float2 E = red2[2][c][0], F = red2[3][c][0];
    float2 qv;
    qv.x = (A.x + B.x + E.x + F.x) * rc0;
    qv.y = (A.y + B.y + E.y + F.y) * rc1;
    Q2s[c] = qv;
  }
  __syncthreads();
  float2 Qq = Q2s[i0 + lane];
  float Qv0 = Qq.x, Qv1 = Qq.y;

  // ---- Pass B: ave_req = (r/T)@M + bf, ave_wsdl = (qv/T)@M + bf ----
  float a0 = 0.f, a1 = 0.f, y0 = 0.f, y1 = 0.f;
#pragma unroll 8
  for (int tt = 0; tt < 64; ++tt) {
    float mk = Mrow[(i0 + tt) * NT + c];  // coalesced
    float s0 = rdlane(rv0, tt), s1 = rdlane(rv1, tt);
    float p0 = rdlane(Qv0, tt), p1 = rdlane(Qv1, tt);
    a0 = fmaf(s0, mk, a0);
    a1 = fmaf(s1, mk, a1);
    y0 = fmaf(p0, mk, y0);
    y1 = fmaf(p1, mk, y1);
  }
  red2[q][c][0] = make_float2(a0, a1);
  red2[q][c][1] = make_float2(y0, y1);
  __syncthreads();
  float st[6];
  {
    float2 A0 = red2[0][c][0], A1 = red2[1][c][0];
    float2 A2 = red2[2][c][0], A3 = red2[3][c][0];
    float2 W0 = red2[0][c][1], W1 = red2[1][c][1];
    float2 W2 = red2[2][c][1], W3 = red2[3][c][1];
    float bfc = bf[c];
    const float invT = 1.0f / NT;
    float avr0 = fmaf(A0.x + A1.x + A2.x + A3.x, invT, bfc);
    float avr1 = fmaf(A0.y + A1.y + A2.y + A3.y, invT, bfc);
    float avw0 = fmaf(W0.x + W1.x + W2.x + W3.x, invT, bfc);
    float avw1 = fmaf(W0.y + W1.y + W2.y + W3.y, invT, bfc);
    st[0] = avr0 * avw0; st[1] = avr0 * avr0; st[2] = avw0 * avw0;
    st[3] = avr1 * avw1; st[4] = avr1 * avr1; st[5] = avw1 * avw1;
  }
  // 4x quad replication of each c cancels in the final ratio.
#pragma unroll
  for (int k = 0; k < 6; ++k)
#pragma unroll
    for (int off = 32; off > 0; off >>= 1) st[k] += __shfl_down(st[k], off, 64);
  if (lane == 0)
#pragma unroll
    for (int k = 0; k < 6; ++k) fin[wid][k] = st[k];
  __syncthreads();
  if (tid < NBATCH) {
    int bb = tid;
    float N = 0.f, A = 0.f, C = 0.f;
    for (int w = 0; w < 16; ++w) {
      N += fin[w][3 * bb + 0];
      A += fin[w][3 * bb + 1];
      C += fin[w][3 * bb + 2];
    }
    out[b0 + bb] = N / fmaxf(sqrtf(A) * sqrtf(C), 1e-8f) * 3.0f;
  }
}

extern "C" void kernel_launch(void* const* d_in, const int* in_sizes, int n_in,
                              void* d_out, int out_size, void* d_ws, size_t ws_size,
                              hipStream_t stream) {
  const float* req  = (const float*)d_in[0];
  const float* wsdl = (const float*)d_in[1];
  const float* TE   = (const float*)d_in[2];
  const float* wf   = (const float*)d_in[3];
  const float* bf   = (const float*)d_in[4];
  float* out = (float*)d_out;

  // ws: [stat(4B), pad to 256 | Mt | Mrow | G2 | u2 | Gd | Gof]
  unsigned* stat = (unsigned*)d_ws;
  float* Mt   = (float*)((char*)d_ws + 256);
  float* Mrow = Mt + NT * NT;
  float* G2   = Mrow + NT * NT;
  float* u2   = G2 + NT * NT;
  float* Gd   = u2 + NT;
  float* Gof  = Gd + NT;

  hipMemsetAsync(d_ws, 0, 16, stream);  // zero stat (capturable)
  k_M<<<NT, 1024, 0, stream>>>(TE, wf, Mt, Mrow);
  k_G<<<NT, 1024, 0, stream>>>(Mt, Mrow, bf, G2, u2, Gd, Gof, stat);
  k_main<<<NB / NBATCH, 1024, 0, stream>>>(req, wsdl, Mrow, G2, u2, Gd, Gof,
                                           stat, bf, out);
}